// Round 13
// baseline (99.622 us; speedup 1.0000x reference)
//
#include <hip/hip_runtime.h>
#include <hip/hip_bf16.h>
#include <math.h>

#define NB 16
#define RB 64
#define HB 128
#define WB 128
#define DB 256
#define HW (HB * WB)

typedef __attribute__((ext_vector_type(8))) short bf16x8;
typedef __attribute__((ext_vector_type(4))) short short4v;
typedef __attribute__((ext_vector_type(4))) float f32x4;

static __device__ __forceinline__ short f2bf(float f) {
  __hip_bfloat16 h = __float2bfloat16(f);
  return *reinterpret_cast<short*>(&h);
}
static __device__ __forceinline__ float bf2f(short s) {
  return __uint_as_float(((unsigned)(unsigned short)s) << 16);
}

// Analytic per-axis max of -(|g-mu|/sg)^2 over grid g_i=(i+0.5)/128:
// attained at the grid point nearest mu (R10-verified bitwise vs reduction).
static __device__ __forceinline__ float axis_maxlog(float mu, float sg) {
  int i = (int)roundf(mu * 128.0f - 0.5f);
  i = i < 0 ? 0 : (i > 127 ? 127 : i);
  const float g = (i + 0.5f) * (1.0f / 128.0f);
  const float tm = fabsf(g - mu) / sg;
  return -(tm * tm);
}

// feat v11: reg-staged double-buffer K-loop (R12-proven for features),
// de-spilled: no exr table; the 8 ex values are recomputed analytically
// per K-step (16 expf/step, hidden under the staging step). Live VGPR ~70
// -> fits the 128-VGPR cap of __launch_bounds__(512,4) -> 2 blocks/CU.
// Grid 512 = (n:16 x kc:32), 512 px (4 h-rows) per block, 16 K-steps.
__global__ __launch_bounds__(512, 4) void feat_kernel(
    const float* __restrict__ x, const float* __restrict__ roi,
    short* __restrict__ partials) {
  __shared__ float buf[2][32 * DB];     // 64 KB -> 2 blocks/CU

  const int bid = blockIdx.x;
  const int n   = bid >> 5;
  const int kc  = bid & 31;
  const int t   = threadIdx.x;
  const int l   = t & 63;
  const int wv  = t >> 6;               // 0..7
  const int mh  = wv >> 2;              // roi half
  const int dw  = wv & 3;               // d-slice
  const int l15 = l & 15;
  const int lk  = (l >> 4) * 8;         // lane's k-offset within a k-step
  const int h0  = kc * 4;               // first h-row of this chunk
  const int dbase = dw * 64 + l15 * 4;

  const f32x4* gx4 =
      reinterpret_cast<const f32x4*>(x + ((size_t)n * HW + (size_t)kc * 512) * DB);

  // ---- prologue: per-rf roi params + ey row values (small register set) ----
  float mux[2], c2x[2], mlx[2];         // c2x = 1/sg_x^2
  float eyv[4][2];                      // [hh][rf_local]
#pragma unroll
  for (int rf = 0; rf < 2; ++rf) {
    const int nr = n * RB + mh * 32 + rf * 16 + l15;
    const float4 rp = reinterpret_cast<const float4*>(roi)[nr];
    const float mlx_ = axis_maxlog(rp.x, rp.z);
    const float mly_ = axis_maxlog(rp.y, rp.w);
    const float em   = expf(mlx_ + mly_);
    const float s    = em / (em + 1e-12f);
    const float isx  = 1.0f / rp.z;
    mux[rf] = rp.x; c2x[rf] = isx * isx; mlx[rf] = mlx_;
#pragma unroll
    for (int hh = 0; hh < 4; ++hh) {
      const float g = (h0 + hh + 0.5f) * (1.0f / 128.0f);
      const float ty = fabsf(g - rp.y) / rp.w;
      eyv[hh][rf] = expf(-(ty * ty) - mly_) * s;
    }
  }

  f32x4 acc[2][4];
#pragma unroll
  for (int rf = 0; rf < 2; ++rf)
#pragma unroll
    for (int f = 0; f < 4; ++f) acc[rf][f] = (f32x4)0.0f;

  f32x4 g0, g1, g2, g3;                 // staging regs (16 VGPR)
#define GLOAD(bi) do {                                                       \
    const f32x4* gp_ = gx4 + (size_t)(bi) * 2048;                            \
    g0 = gp_[t]; g1 = gp_[t + 512]; g2 = gp_[t + 1024]; g3 = gp_[t + 1536];  \
  } while (0)
#define DSWRITE(slot) do {                                                   \
    f32x4* lp_ = reinterpret_cast<f32x4*>(&buf[slot][0]);                    \
    lp_[t] = g0; lp_[t + 512] = g1; lp_[t + 1024] = g2; lp_[t + 1536] = g3;  \
  } while (0)

  // prologue: slot0 filled (compiler inserts vmcnt wait before the write)
  GLOAD(0);
  DSWRITE(0);
  asm volatile("s_waitcnt lgkmcnt(0)" ::: "memory");
  __builtin_amdgcn_s_barrier();
  __builtin_amdgcn_sched_barrier(0);

#define KSTEP(bi) do {                                                       \
    if ((bi) < 15) GLOAD((bi) + 1);                                          \
    const float* bp_ = &buf[(bi) & 1][0];                                    \
    f32x4 xv_[8];                                                            \
    _Pragma("unroll")                                                        \
    for (int j = 0; j < 8; ++j)                                              \
      xv_[j] = *reinterpret_cast<const f32x4*>(                              \
          bp_ + (lk + j) * DB + dbase);                                      \
    bf16x8 bfr_[4];                                                          \
    _Pragma("unroll")                                                        \
    for (int f = 0; f < 4; ++f) {                                            \
      bf16x8 b_;                                                             \
      _Pragma("unroll")                                                      \
      for (int j = 0; j < 8; ++j) b_[j] = f2bf(xv_[j][f]);                   \
      bfr_[f] = b_;                                                          \
    }                                                                        \
    bf16x8 afr_[2];                                                          \
    _Pragma("unroll")                                                        \
    for (int rf = 0; rf < 2; ++rf) {                                         \
      const float ey_ = eyv[(bi) >> 2][rf];                                  \
      bf16x8 a_;                                                             \
      _Pragma("unroll")                                                      \
      for (int i = 0; i < 8; ++i) {                                          \
        const int col = ((bi) & 3) * 32 + lk + i;                            \
        const float g_ = (col + 0.5f) * (1.0f / 128.0f);                     \
        const float d_ = g_ - mux[rf];                                       \
        const float e_ = expf(-(d_ * d_ * c2x[rf]) - mlx[rf]);               \
        a_[i] = f2bf(ey_ * e_);                                              \
      }                                                                      \
      afr_[rf] = a_;                                                         \
    }                                                                        \
    _Pragma("unroll")                                                        \
    for (int rf = 0; rf < 2; ++rf)                                           \
      _Pragma("unroll")                                                      \
      for (int f = 0; f < 4; ++f)                                            \
        acc[rf][f] = __builtin_amdgcn_mfma_f32_16x16x32_bf16(                \
            afr_[rf], bfr_[f], acc[rf][f], 0, 0, 0);                         \
    if ((bi) < 15) DSWRITE(((bi) + 1) & 1);                                  \
    asm volatile("s_waitcnt lgkmcnt(0)" ::: "memory");                       \
    __builtin_amdgcn_s_barrier();                                            \
    __builtin_amdgcn_sched_barrier(0);                                       \
  } while (0)

  KSTEP(0);  KSTEP(1);  KSTEP(2);  KSTEP(3);
  KSTEP(4);  KSTEP(5);  KSTEP(6);  KSTEP(7);
  KSTEP(8);  KSTEP(9);  KSTEP(10); KSTEP(11);
  KSTEP(12); KSTEP(13); KSTEP(14); KSTEP(15);

#undef KSTEP
#undef DSWRITE
#undef GLOAD

  // ---- epilogue: bf16 partial tile, plain coalesced 8B stores ----
  // D layout: col = lane&15 (-> d, +f over vector), row = (lane>>4)*4 + reg.
  short* P = partials + (size_t)bid * (RB * DB);
#pragma unroll
  for (int rf = 0; rf < 2; ++rf) {
#pragma unroll
    for (int reg = 0; reg < 4; ++reg) {
      const int r = mh * 32 + rf * 16 + (l >> 4) * 4 + reg;
      short4v v;
      v.x = f2bf(acc[rf][0][reg]); v.y = f2bf(acc[rf][1][reg]);
      v.z = f2bf(acc[rf][2][reg]); v.w = f2bf(acc[rf][3][reg]);
      *reinterpret_cast<short4v*>(P + (size_t)r * DB + dbase) = v;
    }
  }
}

// Analytic map writer (R10-proven logic: ran as R10's is_map path).
__global__ __launch_bounds__(512) void map_only_kernel(
    const float* __restrict__ roi, float* __restrict__ out_map) {
  __shared__ float sT[1024];
  const int mb = blockIdx.x;            // 0..255, 4 rois each
  const int t  = threadIdx.x;
  float* sEx = sT;
  float* sEy = sT + 512;
  for (int v = t; v < 1024; v += 512) {
    const int rr = v >> 8, axis = (v >> 7) & 1, pos = v & 127;
    const float4 rp = reinterpret_cast<const float4*>(roi)[mb * 4 + rr];
    const float mlx = axis_maxlog(rp.x, rp.z);
    const float mly = axis_maxlog(rp.y, rp.w);
    const float em  = expf(mlx + mly);
    const float s   = em / (em + 1e-12f);
    const float g   = (pos + 0.5f) * (1.0f / 128.0f);
    if (axis == 0) {
      const float tx = fabsf(g - rp.x) / rp.z;
      sEx[rr * 128 + pos] = expf(-(tx * tx) - mlx);
    } else {
      const float ty = fabsf(g - rp.y) / rp.w;
      sEy[rr * 128 + pos] = expf(-(ty * ty) - mly) * s;
    }
  }
  __syncthreads();
  f32x4* dst = reinterpret_cast<f32x4*>(out_map + (size_t)mb * 4 * HW);
#pragma unroll
  for (int p = 0; p < 32; ++p) {
    const int idx = p * 512 + t;
    const int rr = idx >> 12, h = (idx >> 5) & 127, w4 = idx & 31;
    const f32x4 e = *reinterpret_cast<const f32x4*>(&sEx[rr * 128 + w4 * 4]);
    dst[idx] = e * (f32x4)sEy[rr * 128 + h];
  }
}

// Sum 32 bf16 kc-partials per image, apply 1/HW; also copy out_params.
__global__ __launch_bounds__(256) void reduce_kernel(
    const short* __restrict__ partials, const float* __restrict__ roi,
    float* __restrict__ outF, float* __restrict__ out_params) {
  const int idx = blockIdx.x * 256 + threadIdx.x;   // f32x4 index, 65536 total
  const int n   = idx >> 12;                        // 4096 f32x4 per image
  const int i4  = idx & 4095;
  const short4v* p =
      reinterpret_cast<const short4v*>(partials) + (size_t)n * 32 * 4096 + i4;
  f32x4 s = (f32x4)0.0f;
#pragma unroll
  for (int kc = 0; kc < 32; ++kc) {
    const short4v v = p[(size_t)kc * 4096];
    s.x += bf2f(v.x); s.y += bf2f(v.y); s.z += bf2f(v.z); s.w += bf2f(v.w);
  }
  s *= (1.0f / (float)HW);
  reinterpret_cast<f32x4*>(outF)[idx] = s;
  if (idx < NB * RB * 4) out_params[idx] = roi[idx];
}

extern "C" void kernel_launch(void* const* d_in, const int* in_sizes, int n_in,
                              void* d_out, int out_size, void* d_ws, size_t ws_size,
                              hipStream_t stream) {
  const float* x   = (const float*)d_in[0];
  const float* roi = (const float*)d_in[1];
  float* out        = (float*)d_out;
  float* out_feat   = out;                         // 16*64*256
  float* out_params = out + NB * RB * DB;          // 16*64*4
  float* out_map    = out_params + NB * RB * 4;    // 16*64*128*128 (67 MB)

  const size_t par_shorts = 512u * RB * DB;        // 8.39M bf16 (16.8 MB)
  const bool ws_ok = ws_size >= par_shorts * sizeof(short) + 64;

  // Partials in ws (measured ~1 GiB); fallback: out_map head, overwritten
  // by map_only_kernel afterwards (stream-ordered, deterministic).
  short* P = ws_ok ? (short*)d_ws : (short*)out_map;

  feat_kernel<<<512, 512, 0, stream>>>(x, roi, P);
  reduce_kernel<<<256, 256, 0, stream>>>(P, roi, out_feat, out_params);
  map_only_kernel<<<256, 512, 0, stream>>>(roi, out_map);
}